// Round 5
// baseline (312.304 us; speedup 1.0000x reference)
//
#include <hip/hip_runtime.h>

// Problem constants
#define BATCH 4096
#define NI 1024
#define HID 2048
#define TSTEPS 20
#define NA 45
#define TW 256    // fused j-tile width (small tile -> 6 blocks/CU occupancy)
#define SROW 264  // S row stride in bf16 elems (256 + 8 pad)

typedef __bf16 bf16x8 __attribute__((ext_vector_type(8)));
typedef float floatx4 __attribute__((ext_vector_type(4)));

struct StepMeta {
    float ac0, ac1, delta, chosen;
    int chg;    // (oldCol<<8)|newCol applied entering this step, or -1
    int dac, alive, pad;
};

__device__ __forceinline__ unsigned short f2bf(float x) {
    union { float f; unsigned int u; } un; un.f = x;
    unsigned int r = un.u + 0x7FFFu + ((un.u >> 16) & 1u);
    return (unsigned short)(r >> 16);
}

__device__ __forceinline__ ushort4 cvt4(float4 v) {
    ushort4 o;
    o.x = f2bf(v.x); o.y = f2bf(v.y); o.z = f2bf(v.z); o.w = f2bf(v.w);
    return o;
}

// ---------------------------------------------------------------------------
// Kernel 1 (merged prep): transpose_w1 (blocks [0,2048)), convert_w2
// (blocks [2048,2056)), scan (blocks [2056,2072)) — one launch, all
// independent of each other.
// scan: exact fp32 replication of the 20-step state machine. Emits per-step
// absolute state + the one-hot column swap (chg) applied entering this step
// (at most ONE discrete change per step by construction).
// x-column offsets of the extras block: ac0=0 ac1=1 fb=2..4 lr=5..7 jp=8..9
// ss=10..13 at=14..45 delta=46 chosen=47.
// ---------------------------------------------------------------------------
__global__ void prep_kernel(const float* __restrict__ W1, unsigned short* __restrict__ Wt,
                            const float* __restrict__ W2, unsigned short* __restrict__ W2T,
                            const float* __restrict__ camera,
                            const int* __restrict__ fb_in, const int* __restrict__ lr_in,
                            const int* __restrict__ jp_in, const int* __restrict__ ss_in,
                            const int* __restrict__ at_in, StepMeta* __restrict__ meta) {
    __shared__ float tile[32][33];
    int bid = blockIdx.x, tid = threadIdx.x;
    if (bid < 2048) {
        // W1[0:1024][2048] fp32 -> bf16, transposed to Wt[2048][1024]
        int k0 = (bid & 31) * 32, n0 = (bid >> 5) * 32;
        int tx = tid & 31, ty = tid >> 5;  // (32, 8)
        for (int i = 0; i < 4; i++)
            tile[ty + 8 * i][tx] = W1[(size_t)(k0 + ty + 8 * i) * HID + n0 + tx];
        __syncthreads();
        for (int i = 0; i < 4; i++) {
            int n = ty + 8 * i;
            Wt[(size_t)(n0 + n) * NI + k0 + tx] = f2bf(tile[tx][n]);
        }
    } else if (bid < 2056) {
        // W2[2048][45] fp32 -> bf16 transposed W2T[48][2048], rows 45..47 zero
        int k = (bid - 2048) * 256 + tid;  // 0..2047
        for (int n = 0; n < 48; n++)
            W2T[(size_t)n * HID + k] = (n < NA) ? f2bf(W2[(size_t)k * NA + n]) : (unsigned short)0;
    } else {
        int b = (bid - 2056) * 256 + tid;
        if (b >= BATCH) return;
        float cam0 = camera[2 * b], cam1 = camera[2 * b + 1];
        int afb = fb_in[b], alr = lr_in[b], ajp = jp_in[b], ass = ss_in[b], aat = at_in[b];
        float ac0 = 0.f, ac1 = 0.f, delta = 0.0625f;  // MIN_DELTA = 0.5/8
        int rfb = 0, rlr = 0, rjp = 0, rss = 0, rat = 0;
        bool chosen = false, commited = false;
        int cam_steps = 0;
        int chgPending = -1;
        bool camzero = (fabsf(cam0) < 1e-5f) && (fabsf(cam1) < 1e-5f);
        for (int t = 0; t < TSTEPS; t++) {
            StepMeta m;
            m.ac0 = ac0; m.ac1 = ac1; m.delta = delta; m.chosen = chosen ? 1.f : 0.f;
            m.chg = chgPending; chgPending = -1;
            m.alive = commited ? 0 : 1;
            bool commit = (camzero || cam_steps >= 6) &&
                          rfb == afb && rlr == alr && rjp == ajp && rss == ass && rat == aat;
            int dac = 0; bool modified = commit;
            if (!modified && rfb != afb) { dac = (afb == 0 ? rfb - 1 + 6  : afb - 1 + 6 ); chgPending = ((2  + rfb) << 8) | (2  + afb); rfb = afb; modified = true; }
            if (!modified && rlr != alr) { dac = (alr == 0 ? rlr - 1 + 8  : alr - 1 + 8 ); chgPending = ((5  + rlr) << 8) | (5  + alr); rlr = alr; modified = true; }
            if (!modified && rjp != ajp) { dac = (ajp == 0 ? rjp - 1 + 10 : ajp - 1 + 10); chgPending = ((8  + rjp) << 8) | (8  + ajp); rjp = ajp; modified = true; }
            if (!modified && rss != ass) { dac = (ass == 0 ? rss - 1 + 11 : ass - 1 + 11); chgPending = ((10 + rss) << 8) | (10 + ass); rss = ass; modified = true; }
            if (!modified && rat != aat) { dac = (aat == 0 ? rat - 1 + 14 : aat - 1 + 14); chgPending = ((14 + rat) << 8) | (14 + aat); rat = aat; modified = true; }
            // NOTE: reference compares BOTH cam0 and cam1 against ac0 (as-is)
            if (!modified && !chosen &&
                (fabsf(cam0 - ac0) > delta * 2.f || fabsf(cam1 - ac0) > delta * 2.f)) {
                dac = 5; delta = fminf(delta * 2.f, 0.5f); modified = true;
            }
            if (!modified) {
                bool incX = cam0 >= ac0, incY = cam1 >= ac1;
                dac = 1 + (incX ? 1 : 0) + (incY ? 2 : 0);
                ac0 += incX ? delta : -delta;
                ac1 += incY ? delta : -delta;
                delta *= 0.5f;
                chosen = true;
                cam_steps++;
            }
            commited = commited || commit;
            m.dac = dac; m.pad = 0;
            meta[b * TSTEPS + t] = m;
        }
    }
}

// ---------------------------------------------------------------------------
// Kernel 2: base[4096][2048] = fc_input(fp32, converted in-register) @
// W1[:1024] (bf16 MFMA). A-staging: load fp32, cvt->bf16, ds_write_b128
// (removes the separate convert_fc kernel + Ab buffer). B-staging:
// global_load_lds width-16 from pre-transposed Wt. Epilogue folds the
// t=0 constants: + b1 + initial one-hot rows (2,5,8,10,14) + 0.0625*w_delta.
// ---------------------------------------------------------------------------
__global__ __launch_bounds__(256) void gemm_base(const float* __restrict__ A,
                                                 const unsigned short* __restrict__ Wt,
                                                 const float* __restrict__ W1,
                                                 const float* __restrict__ b1,
                                                 float* __restrict__ C) {
    __shared__ __align__(16) __bf16 At[128 * 32];
    __shared__ __align__(16) __bf16 Bt[128 * 32];
    int bn = blockIdx.x, bm = blockIdx.y;
    int m0 = bm * 128, n0 = bn * 128;
    int tid = threadIdx.x;
    int wave = tid >> 6, lane = tid & 63;
    int wr = wave >> 1, wc = wave & 1;
    int l15 = lane & 15, q = lane >> 4;
    floatx4 acc[4][4];
    for (int a = 0; a < 4; a++) for (int c = 0; c < 4; c++) acc[a][c] = (floatx4){0.f, 0.f, 0.f, 0.f};
    int arow = tid >> 1, aseg = (tid & 1) * 16;
    for (int k0 = 0; k0 < NI; k0 += 32) {
        __syncthreads();
        // B: async staged, 2 chunks of 16 B per thread
#pragma unroll
        for (int i = 0; i < 2; i++) {
            int c = i * 256 + tid;
            int row = c >> 2, quarter = c & 3;
            const unsigned short* gB = &Wt[(size_t)(n0 + row) * NI + k0 + quarter * 8];
            __builtin_amdgcn_global_load_lds(
                (const __attribute__((address_space(1))) unsigned int*)gB,
                (__attribute__((address_space(3))) unsigned int*)&Bt[c * 8], 16, 0, 0);
        }
        // A: fp32 load + in-register cvt, 16 elems/thread
        const float* ga = &A[(size_t)(m0 + arow) * NI + k0 + aseg];
        float4 f0 = *(const float4*)&ga[0];
        float4 f1 = *(const float4*)&ga[4];
        float4 f2 = *(const float4*)&ga[8];
        float4 f3 = *(const float4*)&ga[12];
        union { ushort4 s4[4]; uint4 v[2]; } pk;
        pk.s4[0] = cvt4(f0); pk.s4[1] = cvt4(f1); pk.s4[2] = cvt4(f2); pk.s4[3] = cvt4(f3);
        *(uint4*)&At[arow * 32 + aseg]     = pk.v[0];
        *(uint4*)&At[arow * 32 + aseg + 8] = pk.v[1];
        __syncthreads();
        bf16x8 af[4], bf[4];
        for (int mr = 0; mr < 4; mr++)
            af[mr] = *(const bf16x8*)&At[(wr * 64 + mr * 16 + l15) * 32 + q * 8];
        for (int nc = 0; nc < 4; nc++)
            bf[nc] = *(const bf16x8*)&Bt[(wc * 64 + nc * 16 + l15) * 32 + q * 8];
        for (int mr = 0; mr < 4; mr++)
            for (int nc = 0; nc < 4; nc++)
                acc[mr][nc] = __builtin_amdgcn_mfma_f32_16x16x32_bf16(af[mr], bf[nc], acc[mr][nc], 0, 0, 0);
    }
    for (int nc = 0; nc < 4; nc++) {
        int col = n0 + wc * 64 + nc * 16 + l15;
        const float* We = W1 + (size_t)NI * HID + col;
        float cv = b1[col] + We[2 * HID] + We[5 * HID] + We[8 * HID] + We[10 * HID]
                 + We[14 * HID] + 0.0625f * We[46 * HID];
        for (int mr = 0; mr < 4; mr++)
            for (int r = 0; r < 4; r++) {
                int row = m0 + wr * 64 + mr * 16 + q * 4 + r;
                C[(size_t)row * HID + col] = acc[mr][nc][r] + cv;
            }
    }
}

// ---------------------------------------------------------------------------
// Kernel 3: fused per-b MLP + CE. One block per b, 256 threads, 1 j per
// thread, 8 tiles of 256. Small LDS (~23.7 KB) + launch_bounds(256,6) ->
// 6 blocks/CU for latency hiding. Phase A: h[t] = base + u[t]·w + sw[t]
// (swap diffs preloaded; per-t swap schedule packed into scalar selPack —
// no per-t LDS read). silu -> bf16 S (20x256). Phase B: MFMA S @ W2T,
// cross-wave reduce (partials alias dead S), parallel 240-thread CE.
// ---------------------------------------------------------------------------
__global__ __launch_bounds__(256, 6) void fused_mlp(const float* __restrict__ base,
                                                    const float* __restrict__ W1,
                                                    const unsigned short* __restrict__ W2T,
                                                    const float* __restrict__ b2,
                                                    const StepMeta* __restrict__ meta,
                                                    float* __restrict__ loss_out) {
    __shared__ __align__(16) __bf16 S[32 * SROW];        // 16,896 B; rows 20..31 zero
    __shared__ __align__(16) float logitsF[TSTEPS * 48]; // 3,840 B
    __shared__ __align__(16) float4 u4s[TSTEPS];         // (ac0, ac1, delta-d0, chosen)
    __shared__ int chgs[TSTEPS], dacsS[TSTEPS], alivesS[TSTEPS];
    __shared__ int swapL[5], nsS;
    __shared__ float b2s[48];
    __shared__ float ceArr[TSTEPS], afArr[TSTEPS];
    __shared__ float pmax[TSTEPS][12], psum[TSTEPS][12], mxS[TSTEPS];

    int b = blockIdx.x, tid = threadIdx.x;
    int wave = tid >> 6, lane = tid & 63, l15 = lane & 15, q = lane >> 4;

    // zero the MFMA padding rows 20..31
    {
        uint4* z = (uint4*)&S[20 * SROW];
        for (int i = tid; i < 12 * SROW * 2 / 16; i += 256) z[i] = make_uint4(0, 0, 0, 0);
    }
    if (tid < TSTEPS) {
        StepMeta m = meta[b * TSTEPS + tid];
        u4s[tid] = make_float4(m.ac0, m.ac1, m.delta - 0.0625f, m.chosen);
        chgs[tid] = m.chg; dacsS[tid] = m.dac; alivesS[tid] = m.alive;
    }
    if (tid < 48) b2s[tid] = (tid < NA) ? b2[tid] : 0.f;
    __syncthreads();
    if (tid == 0) {
        int ns = 0;
        for (int t = 0; t < TSTEPS; t++) if (chgs[t] >= 0) swapL[ns++] = chgs[t];
        nsS = ns;
        for (; ns < 5; ns++) swapL[ns] = 0;
    }
    __syncthreads();

    // uniform scalar state: swap columns + per-t selection schedule (3b/t)
    int ns = __builtin_amdgcn_readfirstlane(nsS);
    int cA = __builtin_amdgcn_readfirstlane(swapL[0]);
    int cB = __builtin_amdgcn_readfirstlane(swapL[1]);
    int cC = __builtin_amdgcn_readfirstlane(swapL[2]);
    int cD = __builtin_amdgcn_readfirstlane(swapL[3]);
    int cE = __builtin_amdgcn_readfirstlane(swapL[4]);
    int selLo = 0, selHi = 0;  // t 0..9 in selLo, t 10..19 in selHi
    {
        int sc = 0;
        for (int t = 0; t < TSTEPS; t++) {
            int sel = 7;
            if (chgs[t] >= 0) { sel = sc; sc++; }
            if (t < 10) selLo |= sel << (3 * t);
            else        selHi |= sel << (3 * (t - 10));
        }
        selLo = __builtin_amdgcn_readfirstlane(selLo);
        selHi = __builtin_amdgcn_readfirstlane(selHi);
    }

    const float* Wx = W1 + (size_t)NI * HID;
    floatx4 acc[2][3];
    for (int a = 0; a < 2; a++) for (int c = 0; c < 3; c++) acc[a][c] = (floatx4){0.f, 0.f, 0.f, 0.f};
    unsigned short* Su = (unsigned short*)S;

    for (int jt = 0; jt < 8; jt++) {
        if (jt) __syncthreads();                 // phase-B readers of prev tile done
        int j = jt * TW + tid;
        float w0  = Wx[j];
        float w1  = Wx[HID + j];
        float wdl = Wx[46 * HID + j];
        float wch = Wx[47 * HID + j];
        float hb  = base[(size_t)b * HID + j];   // incl. b1 + t0 consts
        float dA = 0.f, dB = 0.f, dC = 0.f, dD = 0.f, dE = 0.f;
        if (ns > 0) dA = Wx[(size_t)(cA & 255) * HID + j] - Wx[(size_t)(cA >> 8) * HID + j];
        if (ns > 1) dB = Wx[(size_t)(cB & 255) * HID + j] - Wx[(size_t)(cB >> 8) * HID + j];
        if (ns > 2) dC = Wx[(size_t)(cC & 255) * HID + j] - Wx[(size_t)(cC >> 8) * HID + j];
        if (ns > 3) dD = Wx[(size_t)(cD & 255) * HID + j] - Wx[(size_t)(cD >> 8) * HID + j];
        if (ns > 4) dE = Wx[(size_t)(cE & 255) * HID + j] - Wx[(size_t)(cE >> 8) * HID + j];
        float sw = 0.f;
#pragma unroll
        for (int t = 0; t < TSTEPS; t++) {
            int sel = (t < 10) ? ((selLo >> (3 * t)) & 7) : ((selHi >> (3 * (t - 10))) & 7);
            if (sel != 7) {  // uniform scalar branch
                float d = (sel == 0) ? dA : (sel == 1) ? dB : (sel == 2) ? dC : (sel == 3) ? dD : dE;
                sw += d;
            }
            float4 u = u4s[t];
            float h = hb + sw + u.x * w0 + u.y * w1 + u.z * wdl + u.w * wch;
            float s = h * __builtin_amdgcn_rcpf(1.f + __expf(-h));
            Su[t * SROW + tid] = f2bf(s);
        }
        __syncthreads();
        // Phase B: wave handles K range [wave*64, wave*64+64) of this j-tile
        const __bf16* Wb = (const __bf16*)W2T;
#pragma unroll
        for (int ks = 0; ks < 2; ks++) {
            int kc = wave * 64 + ks * 32 + q * 8;
            bf16x8 a0 = *(const bf16x8*)&S[l15 * SROW + kc];
            bf16x8 a1 = *(const bf16x8*)&S[(16 + l15) * SROW + kc];
            int kg = jt * TW + kc;
            bf16x8 b0  = *(const bf16x8*)&Wb[(size_t)l15 * HID + kg];
            bf16x8 b1v = *(const bf16x8*)&Wb[(size_t)(16 + l15) * HID + kg];
            bf16x8 b2v = *(const bf16x8*)&Wb[(size_t)(32 + l15) * HID + kg];
            acc[0][0] = __builtin_amdgcn_mfma_f32_16x16x32_bf16(a0, b0,  acc[0][0], 0, 0, 0);
            acc[0][1] = __builtin_amdgcn_mfma_f32_16x16x32_bf16(a0, b1v, acc[0][1], 0, 0, 0);
            acc[0][2] = __builtin_amdgcn_mfma_f32_16x16x32_bf16(a0, b2v, acc[0][2], 0, 0, 0);
            acc[1][0] = __builtin_amdgcn_mfma_f32_16x16x32_bf16(a1, b0,  acc[1][0], 0, 0, 0);
            acc[1][1] = __builtin_amdgcn_mfma_f32_16x16x32_bf16(a1, b1v, acc[1][1], 0, 0, 0);
            acc[1][2] = __builtin_amdgcn_mfma_f32_16x16x32_bf16(a1, b2v, acc[1][2], 0, 0, 0);
        }
    }
    __syncthreads();
    // cross-wave partials into dead S (C/D layout: col=l15, row=q*4+r)
    float* logitsP = (float*)S;                  // 4*960 floats = 15,360 B <= 16,896
    for (int mt = 0; mt < 2; mt++)
        for (int nt = 0; nt < 3; nt++)
            for (int r = 0; r < 4; r++) {
                int t = mt * 16 + q * 4 + r;
                if (t < TSTEPS)
                    logitsP[(wave * TSTEPS + t) * 48 + nt * 16 + l15] = acc[mt][nt][r];
            }
    __syncthreads();
    int tE = tid / 12, gE = tid - tE * 12;
    if (tid < 240) {
        float4 p0 = ((const float4*)logitsP)[tid];
        float4 p1 = ((const float4*)logitsP)[240 + tid];
        float4 p2 = ((const float4*)logitsP)[480 + tid];
        float4 p3 = ((const float4*)logitsP)[720 + tid];
        float4 bb = *(const float4*)&b2s[gE * 4];
        float4 r;
        r.x = p0.x + p1.x + p2.x + p3.x + bb.x;
        r.y = p0.y + p1.y + p2.y + p3.y + bb.y;
        r.z = p0.z + p1.z + p2.z + p3.z + bb.z;
        r.w = p0.w + p1.w + p2.w + p3.w + bb.w;
        ((float4*)logitsF)[tid] = r;
        float lm = (gE == 11) ? r.x : fmaxf(fmaxf(r.x, r.y), fmaxf(r.z, r.w));
        pmax[tE][gE] = lm;
    }
    __syncthreads();
    if (tid < 240 && gE == 0) {
        float m = pmax[tE][0];
        for (int i = 1; i < 12; i++) m = fmaxf(m, pmax[tE][i]);
        mxS[tE] = m;
    }
    __syncthreads();
    if (tid < 240) {
        float m = mxS[tE];
        float4 v = ((const float4*)logitsF)[tid];
        float s;
        if (gE == 11) s = __expf(v.x - m);
        else s = __expf(v.x - m) + __expf(v.y - m) + __expf(v.z - m) + __expf(v.w - m);
        psum[tE][gE] = s;
    }
    __syncthreads();
    if (tid < TSTEPS) {
        float ssum = 0.f;
        for (int i = 0; i < 12; i++) ssum += psum[tid][i];
        float m = mxS[tid];
        int dac = dacsS[tid];
        float ld = logitsF[tid * 48 + dac];
        float ce = -(ld - m - logf(ssum));
        ceArr[tid] = alivesS[tid] ? ce : 0.f;
        afArr[tid] = (float)alivesS[tid];
    }
    __syncthreads();
    if (tid == 0) {
        float s = 0.f, a = 0.f;
        for (int t = 0; t < TSTEPS; t++) { s += ceArr[t]; a += afArr[t]; }
        loss_out[b] = s / a;
    }
}

// ---------------------------------------------------------------------------
// Kernel 4: deterministic final reduction over 4096 per-b losses
// ---------------------------------------------------------------------------
__global__ void reduce_loss(const float* __restrict__ loss, float* __restrict__ out) {
    int tid = threadIdx.x;  // 256
    float s = 0.f;
    for (int i = tid; i < BATCH; i += 256) s += loss[i];
    for (int off = 32; off > 0; off >>= 1) s += __shfl_down(s, off, 64);
    __shared__ float wsum[4];
    if ((tid & 63) == 0) wsum[tid >> 6] = s;
    __syncthreads();
    if (tid == 0) out[0] = (wsum[0] + wsum[1] + wsum[2] + wsum[3]) * (1.0f / (float)BATCH);
}

// ---------------------------------------------------------------------------
extern "C" void kernel_launch(void* const* d_in, const int* in_sizes, int n_in,
                              void* d_out, int out_size, void* d_ws, size_t ws_size,
                              hipStream_t stream) {
    const float* fc_input = (const float*)d_in[0];
    const float* camera   = (const float*)d_in[1];
    const int*   fb       = (const int*)d_in[2];
    const int*   lr       = (const int*)d_in[3];
    const int*   jp       = (const int*)d_in[4];
    const int*   ss       = (const int*)d_in[5];
    const int*   at       = (const int*)d_in[6];
    const float* W1       = (const float*)d_in[7];
    const float* b1       = (const float*)d_in[8];
    const float* W2       = (const float*)d_in[9];
    const float* b2       = (const float*)d_in[10];
    float* out = (float*)d_out;

    char* ws = (char*)d_ws;
    unsigned short* Wt   = (unsigned short*)(ws);                       //  4,194,304 B
    float*          baseB= (float*)(ws + 4194304);                      // 33,554,432 B
    StepMeta*       meta = (StepMeta*)(ws + 37748736);                  //  2,621,440 B
    float*          lossB= (float*)(ws + 40370176);                     //     16,384 B
    unsigned short* W2T  = (unsigned short*)(ws + 40386560);            //    196,608 B

    prep_kernel<<<2048 + 8 + 16, 256, 0, stream>>>(W1, Wt, W2, W2T,
                                                   camera, fb, lr, jp, ss, at, meta);
    gemm_base<<<dim3(HID / 128, BATCH / 128), 256, 0, stream>>>(fc_input, Wt, W1, b1, baseB);
    fused_mlp<<<BATCH, 256, 0, stream>>>(baseB, W1, W2T, b2, meta, lossB);
    reduce_loss<<<1, 256, 0, stream>>>(lossB, out);
}